// Round 5
// baseline (653.949 us; speedup 1.0000x reference)
//
#include <hip/hip_runtime.h>
#include <math.h>

typedef unsigned short u16;
typedef short short8 __attribute__((ext_vector_type(8)));
typedef float floatx4 __attribute__((ext_vector_type(4)));
typedef float floatx16 __attribute__((ext_vector_type(16)));

#define SS 4
#define C_DIM 512
#define L_TOK 1024   // H*W

// ---------- helpers ----------
static __device__ __forceinline__ u16 f2bf(float f) {
  union { float f; unsigned u; } v; v.f = f;
  unsigned u = v.u;
  unsigned r = (u + 0x7fffu + ((u >> 16) & 1u)) >> 16;  // RNE
  return (u16)r;
}

typedef const __attribute__((address_space(1))) void* gvp;
typedef __attribute__((address_space(3))) void* lvp;
#define ASYNC16(g, l) __builtin_amdgcn_global_load_lds((gvp)(g), (lvp)(l), 16, 0, 0)

// ---------- fp32 -> bf16 weight conversion (all 4 weights in one launch) ----------
__global__ __launch_bounds__(256) void convert_all(const float* __restrict__ s0,
                                                   const float* __restrict__ s1,
                                                   const float* __restrict__ s2,
                                                   const float* __restrict__ s3,
                                                   u16* __restrict__ d0, u16* __restrict__ d1,
                                                   u16* __restrict__ d2, u16* __restrict__ d3) {
  int i = blockIdx.x * 256 + threadIdx.x;   // < 786432
  const float* src; u16* dst; int off;
  if (i < 196608)      { src = s0; dst = d0; off = i; }
  else if (i < 262144) { src = s1; dst = d1; off = i - 196608; }
  else if (i < 524288) { src = s2; dst = d2; off = i - 262144; }
  else                 { src = s3; dst = d3; off = i - 524288; }
  float4 v = ((const float4*)src)[off];
  ushort4 o;
  o.x = f2bf(v.x); o.y = f2bf(v.y); o.z = f2bf(v.z); o.w = f2bf(v.w);
  ((ushort4*)dst)[off] = o;
}

// ---------- ada = silu(cond) @ ada_w.T + ada_b  [32, 3072] ----------
__global__ __launch_bounds__(256) void ada_kernel(const float* __restrict__ cond,
                                                  const float* __restrict__ w,
                                                  const float* __restrict__ bias,
                                                  float* __restrict__ ada) {
  int b = blockIdx.y;
  int j = blockIdx.x * 256 + threadIdx.x;   // < 3072
  __shared__ float sc[C_DIM];
  for (int c = threadIdx.x; c < C_DIM; c += 256) {
    float v = cond[b * C_DIM + c];
    sc[c] = v / (1.0f + expf(-v));
  }
  __syncthreads();
  const float* wr = w + (size_t)j * C_DIM;
  float acc = 0.f;
  for (int k = 0; k < C_DIM; k += 4) {
    float4 wv = *(const float4*)&wr[k];
    acc += sc[k] * wv.x + sc[k + 1] * wv.y + sc[k + 2] * wv.z + sc[k + 3] * wv.w;
  }
  ada[(size_t)b * 3072 + j] = acc + bias[j];
}

// ---------- rpbT[head][q][k] + per-window mask bitwords ----------
__global__ __launch_bounds__(64) void prep_attn(const float* __restrict__ rpb,
                                                float* __restrict__ rpbT,
                                                unsigned long long* __restrict__ maskbits) {
  int q = blockIdx.x;        // 64
  int head = blockIdx.y;     // 16
  int k = threadIdx.x;       // 64
  int i1 = q >> 3, j1 = q & 7, i2 = k >> 3, j2 = k & 7;
  rpbT[((size_t)head * 64 + q) * 64 + k] =
      rpb[((i1 - i2 + 7) * 15 + (j1 - j2 + 7)) * 16 + head];
  if (head == 0) {
    for (int widx = 0; widx < 16; widx++) {
      int wh = widx >> 2, wwi = widx & 3;
      int hq = wh * 8 + i1, wq = wwi * 8 + j1;
      int hk = wh * 8 + i2, wk = wwi * 8 + j2;
      int rq = ((hq < 24) ? 0 : (hq < 28) ? 1 : 2) * 3 + ((wq < 24) ? 0 : (wq < 28) ? 1 : 2);
      int rk = ((hk < 24) ? 0 : (hk < 28) ? 1 : 2) * 3 + ((wk < 24) ? 0 : (wk < 28) ? 1 : 2);
      unsigned long long m = __ballot(rq != rk);
      if (k == 0) maskbits[widx * 64 + q] = m;
    }
  }
}

// ---------- LN + modulate (+ optional roll/window gather), output bf16 ----------
template <int MODE>
__global__ __launch_bounds__(128) void ln_mod(const float* __restrict__ x,
                                              const float* __restrict__ ada,
                                              const float* __restrict__ nw,
                                              const float* __restrict__ nb,
                                              u16* __restrict__ out) {
  int m = blockIdx.x;           // output row (window layout for MODE 0)
  int b = m >> 10;
  size_t srow;
  if (MODE == 0) {
    int n = m & 63, widx = (m >> 6) & 15;
    int wh = widx >> 2, wwi = widx & 3;
    int i = n >> 3, j = n & 7;
    int hs = (wh * 8 + i + SS) & 31;
    int ws_ = (wwi * 8 + j + SS) & 31;
    srow = (size_t)b * L_TOK + hs * 32 + ws_;
  } else {
    srow = (size_t)m;
  }
  const float* src = x + srow * C_DIM;
  int t = threadIdx.x;
  float4 v = *(const float4*)&src[t * 4];
  float s = v.x + v.y + v.z + v.w;
  float ss = v.x * v.x + v.y * v.y + v.z * v.z + v.w * v.w;
#pragma unroll
  for (int off = 32; off > 0; off >>= 1) {
    s += __shfl_down(s, off);
    ss += __shfl_down(ss, off);
  }
  __shared__ float red[4];
  if ((t & 63) == 0) { red[(t >> 6) * 2] = s; red[(t >> 6) * 2 + 1] = ss; }
  __syncthreads();
  float mean = (red[0] + red[2]) * (1.f / C_DIM);
  float var = (red[1] + red[3]) * (1.f / C_DIM) - mean * mean;
  float rstd = rsqrtf(var + 1e-5f);
  const float* sh = ada + (size_t)b * 3072 + (MODE ? 1536 : 0);
  const float* scm = ada + (size_t)b * 3072 + (MODE ? 2048 : 512);
  int c = t * 4;
  ushort4 o;
  {
    float y;
    y = ((v.x - mean) * rstd * nw[c + 0] + nb[c + 0]) * (1.f + scm[c + 0]) + sh[c + 0]; o.x = f2bf(y);
    y = ((v.y - mean) * rstd * nw[c + 1] + nb[c + 1]) * (1.f + scm[c + 1]) + sh[c + 1]; o.y = f2bf(y);
    y = ((v.z - mean) * rstd * nw[c + 2] + nb[c + 2]) * (1.f + scm[c + 2]) + sh[c + 2]; o.z = f2bf(y);
    y = ((v.w - mean) * rstd * nw[c + 3] + nb[c + 3]) * (1.f + scm[c + 3]) + sh[c + 3]; o.w = f2bf(y);
  }
  *(ushort4*)&out[(size_t)m * C_DIM + c] = o;
}

// ---------- bf16 MFMA GEMM v3: 32x32x16 MFMA + XOR-swizzled LDS ----------
// LDS tile [128][64] u16, contiguous. Granule (16B=8 u16) j of row r holds
// GLOBAL granule j^(r&7); async DMA dst = base+lane*16 with the inverse
// swizzle folded into the SOURCE address ((l&7)^(l>>3), wave-uniform).
// Frag reads: consecutive-8-lane batches then tile all 32 banks -> no conflicts.
// C^T register layout via mfma(a=W-frag, b=X-frag); 32x32 C/D map:
//   out_row = lane&31, out_col = (reg&3) + 8*(reg>>2) + 4*(lane>>5).
// EPI 0: bias -> bf16 | 1: +tanh-GELU -> bf16 | 2: window-reverse scatter,
// x + g_msa*v -> fp32 d_out | 3: d_out += g_mlp*v in place.
template <int EPI>
__global__ __launch_bounds__(256, 2) void gemm_bf16(
    const u16* __restrict__ A, const u16* __restrict__ Bw,
    const float* __restrict__ bias, int K, int N,
    u16* __restrict__ outBf, float* __restrict__ outF,
    const float* __restrict__ resid, const float* __restrict__ ada) {
  __shared__ __align__(16) u16 lA[128 * 64];
  __shared__ __align__(16) u16 lB[128 * 64];
  const int tid = threadIdx.x;
  const int lane = tid & 63, wave = tid >> 6;
  const int wr = wave >> 1, wc = wave & 1;
  // XCD swizzle (bijection)
  const int gx = gridDim.x;
  const int id = blockIdx.y * gx + blockIdx.x;
  const int per = (gx * gridDim.y) >> 3;
  const int nid = (id & 7) * per + (id >> 3);
  const int rowA0 = (nid / gx) * 128;
  const int colB0 = (nid % gx) * 128;

  floatx16 acc[2][2];
#pragma unroll
  for (int a = 0; a < 2; a++)
#pragma unroll
    for (int b = 0; b < 2; b++)
#pragma unroll
      for (int r = 0; r < 16; r++) acc[a][b][r] = 0.f;

  // staging: dst row = tid>>3 within each 32-row band, dst granule = lane&7,
  // source k-granule = (lane&7)^(lane>>3)  (so LDS granule j holds global j^(r&7))
  const int srow = tid >> 3;                       // 0..31
  const int gsw = ((lane & 7) ^ (lane >> 3)) * 8;  // u16 offset within k-tile
  const u16* gA = &A[(size_t)(rowA0 + srow) * K + gsw];
  const u16* gB = &Bw[(size_t)(colB0 + srow) * K + gsw];
  u16* lAw = &lA[wave * 512];
  u16* lBw = &lB[wave * 512];
  const size_t rb = (size_t)32 * K;  // 32-row band stride in global

  const int m = lane & 31, half = lane >> 5;
  const int w7 = m & 7;

  for (int k0 = 0; k0 < K; k0 += 64) {
    ASYNC16(gA + k0, lAw);
    ASYNC16(gA + k0 + rb, lAw + 2048);
    ASYNC16(gA + k0 + 2 * rb, lAw + 4096);
    ASYNC16(gA + k0 + 3 * rb, lAw + 6144);
    ASYNC16(gB + k0, lBw);
    ASYNC16(gB + k0 + rb, lBw + 2048);
    ASYNC16(gB + k0 + 2 * rb, lBw + 4096);
    ASYNC16(gB + k0 + 3 * rb, lBw + 6144);
    __syncthreads();
#pragma unroll
    for (int s = 0; s < 4; s++) {
      const int go = (((2 * s) | half) ^ w7) * 8;   // swizzled granule offset (u16)
      short8 x0 = *(const short8*)&lA[(wr * 64 + m) * 64 + go];
      short8 x1 = *(const short8*)&lA[(wr * 64 + 32 + m) * 64 + go];
      short8 w0 = *(const short8*)&lB[(wc * 64 + m) * 64 + go];
      short8 w1 = *(const short8*)&lB[(wc * 64 + 32 + m) * 64 + go];
      acc[0][0] = __builtin_amdgcn_mfma_f32_32x32x16_bf16(w0, x0, acc[0][0], 0, 0, 0);
      acc[0][1] = __builtin_amdgcn_mfma_f32_32x32x16_bf16(w1, x0, acc[0][1], 0, 0, 0);
      acc[1][0] = __builtin_amdgcn_mfma_f32_32x32x16_bf16(w0, x1, acc[1][0], 0, 0, 0);
      acc[1][1] = __builtin_amdgcn_mfma_f32_32x32x16_bf16(w1, x1, acc[1][1], 0, 0, 0);
    }
    __syncthreads();
  }

  // acc[mi][ni]: C[row = rowA0+wr*64+mi*32+m][col = colB0+wc*64+ni*32+(reg&3)+8*(reg>>2)+4*half]
#pragma unroll
  for (int mi = 0; mi < 2; mi++) {
    const int row = rowA0 + wr * 64 + mi * 32 + m;
    size_t dstrow;
    const float* gvec = nullptr;
    if (EPI == 2) {
      int b = row >> 10;
      int n = row & 63, widx = (row >> 6) & 15;
      int wh = widx >> 2, wwi = widx & 3;
      int i = n >> 3, j = n & 7;
      int hd = (wh * 8 + i + SS) & 31;
      int wd = (wwi * 8 + j + SS) & 31;
      dstrow = ((size_t)b * L_TOK + hd * 32 + wd) * C_DIM;
      gvec = ada + (size_t)b * 3072 + 1024;
    } else if (EPI == 3) {
      dstrow = (size_t)row * C_DIM;
      gvec = ada + (size_t)(row >> 10) * 3072 + 2560;
    }
#pragma unroll
    for (int ni = 0; ni < 2; ni++) {
#pragma unroll
      for (int a = 0; a < 4; a++) {
        const int col0 = colB0 + wc * 64 + ni * 32 + a * 8 + half * 4;
        float4 bv = *(const float4*)&bias[col0];
        float v0 = acc[mi][ni][a * 4 + 0] + bv.x;
        float v1 = acc[mi][ni][a * 4 + 1] + bv.y;
        float v2 = acc[mi][ni][a * 4 + 2] + bv.z;
        float v3 = acc[mi][ni][a * 4 + 3] + bv.w;
        if (EPI == 1) {  // tanh-form GELU
          v0 = __fdividef(v0, 1.f + __expf(-v0 * (1.59576912f + 0.07135481f * v0 * v0)));
          v1 = __fdividef(v1, 1.f + __expf(-v1 * (1.59576912f + 0.07135481f * v1 * v1)));
          v2 = __fdividef(v2, 1.f + __expf(-v2 * (1.59576912f + 0.07135481f * v2 * v2)));
          v3 = __fdividef(v3, 1.f + __expf(-v3 * (1.59576912f + 0.07135481f * v3 * v3)));
        }
        if (EPI == 0 || EPI == 1) {
          ushort4 pk;
          pk.x = f2bf(v0); pk.y = f2bf(v1); pk.z = f2bf(v2); pk.w = f2bf(v3);
          *(ushort4*)&outBf[(size_t)row * N + col0] = pk;
        } else if (EPI == 2) {
          size_t dst = dstrow + col0;
          float4 rs = *(const float4*)&resid[dst];
          float4 g = *(const float4*)&gvec[col0];
          float4 o;
          o.x = rs.x + g.x * v0; o.y = rs.y + g.y * v1;
          o.z = rs.z + g.z * v2; o.w = rs.w + g.w * v3;
          *(float4*)&outF[dst] = o;
        } else {
          size_t dst = dstrow + col0;
          float4 cur = *(const float4*)&outF[dst];
          float4 g = *(const float4*)&gvec[col0];
          float4 o;
          o.x = cur.x + g.x * v0; o.y = cur.y + g.y * v1;
          o.z = cur.z + g.z * v2; o.w = cur.w + g.w * v3;
          *(float4*)&outF[dst] = o;
        }
      }
    }
  }
}

// ---------- MFMA windowed attention: one single-wave block per (window, head) ----------
__global__ __launch_bounds__(64, 4) void attn_mfma(const u16* __restrict__ qkv,
                                                   const float* __restrict__ rpbT,
                                                   const unsigned long long* __restrict__ maskbits,
                                                   u16* __restrict__ out) {
  __shared__ __align__(16) u16 VT[32 * 72];  // V^T, stride 72
  __shared__ __align__(16) u16 P[64 * 72];   // P, stride 72
  const int lane = threadIdx.x;
  const int col = lane & 15, quad = lane >> 4;
  const int id = blockIdx.x;                 // 8192 = 512 windows * 16 heads
  const int w_ = id >> 4, head = id & 15;
  const int widx = w_ & 15;
  const u16* base = qkv + (size_t)w_ * 64 * 1536 + head * 32;

  {
    const u16* vrow = base + 1024 + (size_t)lane * 1536;
#pragma unroll
    for (int c = 0; c < 4; c++) {
      uint4 u = *(const uint4*)&vrow[c * 8];
      unsigned uu0 = u.x, uu1 = u.y, uu2 = u.z, uu3 = u.w;
      VT[(c * 8 + 0) * 72 + lane] = (u16)(uu0 & 0xffff);
      VT[(c * 8 + 1) * 72 + lane] = (u16)(uu0 >> 16);
      VT[(c * 8 + 2) * 72 + lane] = (u16)(uu1 & 0xffff);
      VT[(c * 8 + 3) * 72 + lane] = (u16)(uu1 >> 16);
      VT[(c * 8 + 4) * 72 + lane] = (u16)(uu2 & 0xffff);
      VT[(c * 8 + 5) * 72 + lane] = (u16)(uu2 >> 16);
      VT[(c * 8 + 6) * 72 + lane] = (u16)(uu3 & 0xffff);
      VT[(c * 8 + 7) * 72 + lane] = (u16)(uu3 >> 16);
    }
  }

  short8 kf[4], qf[4];
#pragma unroll
  for (int mi = 0; mi < 4; mi++)
    kf[mi] = *(const short8*)(base + 512 + (size_t)(mi * 16 + col) * 1536 + quad * 8);
#pragma unroll
  for (int ni = 0; ni < 4; ni++)
    qf[ni] = *(const short8*)(base + (size_t)(ni * 16 + col) * 1536 + quad * 8);

  floatx4 st[4][4];
#pragma unroll
  for (int mi = 0; mi < 4; mi++)
#pragma unroll
    for (int ni = 0; ni < 4; ni++) st[mi][ni] = (floatx4){0.f, 0.f, 0.f, 0.f};
#pragma unroll
  for (int mi = 0; mi < 4; mi++)
#pragma unroll
    for (int ni = 0; ni < 4; ni++)
      st[mi][ni] = __builtin_amdgcn_mfma_f32_16x16x32_bf16(kf[mi], qf[ni], st[mi][ni], 0, 0, 0);

  const float scale = 0.17677669529663687f;  // 32^-0.5
  float invq[4];
#pragma unroll
  for (int ni = 0; ni < 4; ni++) {
    int q = ni * 16 + col;
    unsigned long long mw = maskbits[widx * 64 + q];
    const float* rp = rpbT + ((size_t)head * 64 + q) * 64;
    float mx = -1e30f;
#pragma unroll
    for (int mi = 0; mi < 4; mi++) {
      floatx4 r4 = *(const floatx4*)&rp[mi * 16 + quad * 4];
#pragma unroll
      for (int r = 0; r < 4; r++) {
        int key = mi * 16 + quad * 4 + r;
        float s = st[mi][ni][r] * scale + r4[r];
        s -= ((mw >> key) & 1ull) ? 100.f : 0.f;
        st[mi][ni][r] = s;
        mx = fmaxf(mx, s);
      }
    }
    mx = fmaxf(mx, __shfl_xor(mx, 16));
    mx = fmaxf(mx, __shfl_xor(mx, 32));
    float sum = 0.f;
#pragma unroll
    for (int mi = 0; mi < 4; mi++) {
      float e0 = __expf(st[mi][ni][0] - mx);
      float e1 = __expf(st[mi][ni][1] - mx);
      float e2 = __expf(st[mi][ni][2] - mx);
      float e3 = __expf(st[mi][ni][3] - mx);
      sum += e0 + e1 + e2 + e3;
      ushort4 pk;
      pk.x = f2bf(e0); pk.y = f2bf(e1); pk.z = f2bf(e2); pk.w = f2bf(e3);
      *(ushort4*)&P[q * 72 + mi * 16 + quad * 4] = pk;
    }
    sum += __shfl_xor(sum, 16);
    sum += __shfl_xor(sum, 32);
    invq[ni] = 1.f / sum;
  }
  __syncthreads();

  floatx4 o[2][4];
#pragma unroll
  for (int mt = 0; mt < 2; mt++)
#pragma unroll
    for (int nt = 0; nt < 4; nt++) o[mt][nt] = (floatx4){0.f, 0.f, 0.f, 0.f};
#pragma unroll
  for (int kc = 0; kc < 2; kc++) {
    short8 vf0 = *(const short8*)&VT[(col) * 72 + kc * 32 + quad * 8];
    short8 vf1 = *(const short8*)&VT[(16 + col) * 72 + kc * 32 + quad * 8];
#pragma unroll
    for (int nt = 0; nt < 4; nt++) {
      short8 pf = *(const short8*)&P[(nt * 16 + col) * 72 + kc * 32 + quad * 8];
      o[0][nt] = __builtin_amdgcn_mfma_f32_16x16x32_bf16(vf0, pf, o[0][nt], 0, 0, 0);
      o[1][nt] = __builtin_amdgcn_mfma_f32_16x16x32_bf16(vf1, pf, o[1][nt], 0, 0, 0);
    }
  }

#pragma unroll
  for (int mt = 0; mt < 2; mt++)
#pragma unroll
    for (int nt = 0; nt < 4; nt++) {
      int q = nt * 16 + col;
      float iv = invq[nt];
      ushort4 pk;
      pk.x = f2bf(o[mt][nt][0] * iv);
      pk.y = f2bf(o[mt][nt][1] * iv);
      pk.z = f2bf(o[mt][nt][2] * iv);
      pk.w = f2bf(o[mt][nt][3] * iv);
      *(ushort4*)&out[((size_t)w_ * 64 + q) * 512 + head * 32 + mt * 16 + quad * 4] = pk;
    }
}

// ---------- launch ----------
extern "C" void kernel_launch(void* const* d_in, const int* in_sizes, int n_in,
                              void* d_out, int out_size, void* d_ws, size_t ws_size,
                              hipStream_t stream) {
  const float* x      = (const float*)d_in[0];
  const float* cond   = (const float*)d_in[1];
  const float* n1w    = (const float*)d_in[2];
  const float* n1b    = (const float*)d_in[3];
  const float* qkv_w  = (const float*)d_in[4];
  const float* qkv_b  = (const float*)d_in[5];
  const float* rpb    = (const float*)d_in[6];
  const float* proj_w = (const float*)d_in[7];
  const float* proj_b = (const float*)d_in[8];
  const float* n2w    = (const float*)d_in[9];
  const float* n2b    = (const float*)d_in[10];
  const float* fc1_w  = (const float*)d_in[11];
  const float* fc1_b  = (const float*)d_in[12];
  const float* fc2_w  = (const float*)d_in[13];
  const float* fc2_b  = (const float*)d_in[14];
  const float* ada_w  = (const float*)d_in[15];
  const float* ada_b  = (const float*)d_in[16];
  float* out = (float*)d_out;
  char* ws = (char*)d_ws;

  // workspace layout (bytes)
  u16*  qkvw_bf  = (u16*)(ws + 0);              // 1,572,864
  u16*  projw_bf = (u16*)(ws + 1572864);        //   524,288
  u16*  fc1w_bf  = (u16*)(ws + 2097152);        // 2,097,152
  u16*  fc2w_bf  = (u16*)(ws + 4194304);        // 2,097,152
  float* ada     = (float*)(ws + 6291456);      //   393,216
  float* rpbT    = (float*)(ws + 6684672);      //   262,144
  unsigned long long* maskb = (unsigned long long*)(ws + 6946816);  // 8,192
  u16*  hw       = (u16*)(ws + 6955008);        // 33,554,432
  u16*  qkvo     = (u16*)(ws + 40509440);       // 100,663,296
  u16*  attno    = (u16*)(ws + 141172736);      // 33,554,432
  u16*  mlp      = (u16*)(ws + 40509440);       // 134,217,728 (reuses qkvo+attno)
  // total 174,727,168 bytes

  convert_all<<<3072, 256, 0, stream>>>(qkv_w, proj_w, fc1_w, fc2_w,
                                        qkvw_bf, projw_bf, fc1w_bf, fc2w_bf);
  prep_attn<<<dim3(64, 16), 64, 0, stream>>>(rpb, rpbT, maskb);

  ada_kernel<<<dim3(12, 32), 256, 0, stream>>>(cond, ada_w, ada_b, ada);
  ln_mod<0><<<32768, 128, 0, stream>>>(x, ada, n1w, n1b, hw);
  gemm_bf16<0><<<dim3(12, 256), 256, 0, stream>>>(hw, qkvw_bf, qkv_b, 512, 1536,
                                                  qkvo, nullptr, nullptr, nullptr);
  attn_mfma<<<8192, 64, 0, stream>>>(qkvo, rpbT, maskb, attno);
  gemm_bf16<2><<<dim3(4, 256), 256, 0, stream>>>(attno, projw_bf, proj_b, 512, 512,
                                                 nullptr, out, x, ada);
  ln_mod<1><<<32768, 128, 0, stream>>>(out, ada, n2w, n2b, hw);
  gemm_bf16<1><<<dim3(16, 256), 256, 0, stream>>>(hw, fc1w_bf, fc1_b, 512, 2048,
                                                  mlp, nullptr, nullptr, nullptr);
  gemm_bf16<3><<<dim3(4, 256), 256, 0, stream>>>(mlp, fc2w_bf, fc2_b, 2048, 512,
                                                 nullptr, out, nullptr, ada);
}